// Round 6
// baseline (5194.935 us; speedup 1.0000x reference)
//
#include <hip/hip_runtime.h>

#define TT 365
#define BB 512
#define DD 16
#define HH 256
#define SS 32

typedef __attribute__((ext_vector_type(8))) short short8;
typedef __attribute__((ext_vector_type(4))) float f32x4;
typedef unsigned long long u64;

__device__ __host__ inline short f2bf(float f){
  union { float f; unsigned u; } v; v.f = f;
  unsigned r = v.u + 0x7FFFu + ((v.u >> 16) & 1u);
  return (short)(r >> 16);
}
__device__ inline float sigm(float x){ return 1.0f/(1.0f+__expf(-x)); }
__device__ inline float tanhx(float x){ return 2.0f/(1.0f+__expf(-2.0f*x)) - 1.0f; }

// A-fragment address (shorts) in an 8KB K=256 region for mfma_16x16x32 A-layout.
__device__ inline int fragAddr(int k, int m){
  return ((k>>5)*512) + ((((k&31)>>3)*16 + m)*8) + (k&7);
}

// ---------------- prep kernels ----------------
__global__ void prep_weights(const float* __restrict__ Wih0, const float* __restrict__ Whh0,
                             const float* __restrict__ Wih1, const float* __restrict__ Whh1,
                             short* __restrict__ Wb0, short* __restrict__ Wb1)
{
  int idx = blockIdx.x*blockDim.x + threadIdx.x;
  const int n0 = 16*36*512;
  const int n1 = 16*64*512;
  if (idx < n0){
    int frag = idx >> 9, pos = idx & 511;
    int lane = pos >> 3, jj = pos & 7;
    int slot = frag / 36, rem = frag % 36;
    int ks = rem >> 2, nt = rem & 3;
    int n = nt*256 + slot*16 + (lane & 15);
    float v = 0.0f;
    if (ks == 0){
      int k32 = (lane>>4)*8 + jj;
      if (k32 < 16) v = Wih0[n*16 + k32];
    } else {
      int k = (ks-1)*32 + (lane>>4)*8 + jj;
      v = Whh0[n*256 + k];
    }
    Wb0[idx] = f2bf(v);
  } else if (idx < n0 + n1){
    int e = idx - n0;
    int frag = e >> 9, pos = e & 511;
    int lane = pos >> 3, jj = pos & 7;
    int slot = frag >> 6, rem = frag & 63;
    int ks = rem >> 2, nt = rem & 3;
    int n = nt*256 + slot*16 + (lane & 15);
    int k = ks*32 + (lane>>4)*8 + jj;
    float v = (k < 256) ? Wih1[n*256 + k] : Whh1[n*256 + (k-256)];
    Wb1[e] = f2bf(v);
  }
}

__global__ void prep_h0(const float* __restrict__ xs, const float* __restrict__ Ws,
                        const float* __restrict__ bs, float* __restrict__ h0init)
{
  int i = blockIdx.x*blockDim.x + threadIdx.x;
  int b = i >> 8, jj = i & 255;
  float s = bs[jj];
  const float* xr = xs + b*SS;
  const float* wr = Ws + jj*SS;
#pragma unroll
  for (int q=0;q<SS;++q) s += xr[q]*wr[q];
  h0init[i] = s;
}

__global__ void prep_bias(const float* __restrict__ a0, const float* __restrict__ a1,
                          const float* __restrict__ a2, const float* __restrict__ a3,
                          float* __restrict__ b0o, float* __restrict__ b1o)
{
  int i = threadIdx.x + blockIdx.x*blockDim.x;
  if (i < 1024) b0o[i] = a0[i] + a1[i];
  else if (i < 2048) b1o[i-1024] = a2[i-1024] + a3[i-1024];
}

__global__ void prep_zero(float* __restrict__ out, unsigned* __restrict__ flags)
{
  int i = blockIdx.x*blockDim.x + threadIdx.x;
  if (i < BB*TT) out[i] = 0.0f;
  if (i < 4096) flags[i] = 0u;
}

// ---------------- persistent fused LSTM ----------------
// 64 blocks x 256 threads; role c = bid>>4 (64 hidden cols), group-pair gp = bid&15
// => contexts gA=2*gp, gB=2*gp+1 (16 batch rows each). Weights register/AGPR-resident,
// SHARED by both contexts. Lag pipeline per context: superstep s = L0@t=s + L1@t=s-1.
// ZERO atomic RMWs in the loop: publishes = relaxed agent atomic stores (write-through,
// fire-and-forget); flag = RELEASE store by one lane (implicit L2 writeback = insurance
// that ring data reached the coherence point); polls = 3 lanes/context, relaxed spin
// with acquire exit (buffer_inv) so the following plain vector reads are fresh.
// Context B's compute overlaps context A's publish/poll latency; waits run concurrently.
__global__ __launch_bounds__(256, 1) void lstm_fused(
    const short* __restrict__ Wb0, const short* __restrict__ Wb1,
    const float* __restrict__ h0i, const float* __restrict__ b0c,
    const float* __restrict__ b1c, const float* __restrict__ x,
    const float* __restrict__ Wo, const float* __restrict__ bo,
    short* __restrict__ ring0, short* __restrict__ ring1,
    unsigned* __restrict__ flags, float* __restrict__ out)
{
  __shared__ alignas(16) short AX[2][512];
  __shared__ alignas(16) short AH0[2][4096];
  __shared__ alignas(16) short AH1[2][4096];
  __shared__ float outacc[2][16][4];
  __shared__ float outLDS[2][TT][16];      // 46.7 KB

  const int tid  = threadIdx.x;
  const int w    = tid >> 6;
  const int lane = tid & 63;
  const int col16= lane & 15;
  const int quad = lane >> 4;
  const int c    = blockIdx.x >> 4;        // 0..3
  const int gp   = blockIdx.x & 15;        // 0..15
  const int slot = c*4 + w;
  const int colg = slot*16 + col16;
  int gctx[2]; gctx[0] = gp*2; gctx[1] = gp*2+1;

  // ---- register-resident weight fragments (shared across contexts) ----
  short8 F0[36], F1[64];
  {
    const short8* p0 = (const short8*)Wb0 + slot*36*64 + lane;
#pragma unroll
    for (int f=0; f<36; ++f) F0[f] = p0[f*64];
    const short8* p1 = (const short8*)Wb1 + slot*64*64 + lane;
#pragma unroll
    for (int f=0; f<64; ++f) F1[f] = p1[f*64];
  }
  float bia0[4], bia1[4];
#pragma unroll
  for (int nt=0; nt<4; ++nt){
    bia0[nt] = b0c[nt*256 + slot*16 + col16];
    bia1[nt] = b1c[nt*256 + slot*16 + col16];
  }
  const float wo = Wo[colg];

  // ---- init both contexts ----
  float c0s[2][4], c1s[2][4];
#pragma unroll
  for (int ctx=0; ctx<2; ++ctx){
    int rowbase = gctx[ctx]*16;
#pragma unroll
    for (int r=0; r<4; ++r){
      c0s[ctx][r] = h0i[(rowbase + quad*4 + r)*HH + colg];
      c1s[ctx][r] = c0s[ctx][r];
    }
    for (int i = tid; i < 4096; i += 256){
      int m = i >> 8, k = i & 255;
      short v = f2bf(h0i[(rowbase+m)*HH + k]);
      AH0[ctx][fragAddr(k,m)] = v;
      AH1[ctx][fragAddr(k,m)] = v;
    }
    {
      int m = tid >> 4, d = tid & 15;
      AX[ctx][fragAddr(d, m)]      = f2bf(x[(rowbase+m)*TT*DD + d]);
      AX[ctx][fragAddr(16 + d, m)] = 0;
    }
  }
  __syncthreads();

  const f32x4 zero = {0.0f,0.0f,0.0f,0.0f};

  for (int s=0; s<=TT; ++s){
    const bool doL0 = (s < TT);
    const bool doL1 = (s >= 1);

    float h0v[2][4], h1v[2][4];
    float xf[2];

    // ---- Phase 1: compute + publish for both contexts ----
#pragma unroll
    for (int ctx=0; ctx<2; ++ctx){
      int g = gctx[ctx];
      int rowbase = g*16;

      xf[ctx] = 0.0f;
      if (s+1 < TT){
        int m = tid >> 4, d = tid & 15;
        xf[ctx] = x[(rowbase+m)*TT*DD + (s+1)*DD + d];
      }

      f32x4 acc0[4], acc1[4];
#pragma unroll
      for (int nt=0; nt<4; ++nt){ acc0[nt]=zero; acc1[nt]=zero; }
      if (doL0){
        short8 a = *(const short8*)(AX[ctx] + lane*8);
#pragma unroll
        for (int nt=0; nt<4; ++nt)
          acc0[nt] = __builtin_amdgcn_mfma_f32_16x16x32_bf16(a, F0[nt], acc0[nt], 0,0,0);
      }
#pragma unroll
      for (int ks=0; ks<8; ++ks){
        short8 a = *(const short8*)(AH0[ctx] + ks*512 + lane*8);
        if (doL0){
#pragma unroll
          for (int nt=0; nt<4; ++nt)
            acc0[nt] = __builtin_amdgcn_mfma_f32_16x16x32_bf16(a, F0[(ks+1)*4+nt], acc0[nt], 0,0,0);
        }
        if (doL1){
#pragma unroll
          for (int nt=0; nt<4; ++nt)
            acc1[nt] = __builtin_amdgcn_mfma_f32_16x16x32_bf16(a, F1[ks*4+nt], acc1[nt], 0,0,0);
        }
      }
      if (doL1){
#pragma unroll
        for (int ks=0; ks<8; ++ks){
          short8 a = *(const short8*)(AH1[ctx] + ks*512 + lane*8);
#pragma unroll
          for (int nt=0; nt<4; ++nt)
            acc1[nt] = __builtin_amdgcn_mfma_f32_16x16x32_bf16(a, F1[32+ks*4+nt], acc1[nt], 0,0,0);
        }
      }

      if (doL0){
#pragma unroll
        for (int r=0; r<4; ++r){
          float iv = sigm (acc0[0][r] + bia0[0]);
          float fv = sigm (acc0[1][r] + bia0[1]);
          float gv = tanhx(acc0[2][r] + bia0[2]);
          float ov = sigm (acc0[3][r] + bia0[3]);
          float cc = fv*c0s[ctx][r] + iv*gv;
          c0s[ctx][r] = cc;
          h0v[ctx][r] = ov * tanhx(cc);
        }
        // publish h0: relaxed agent atomic store (no RMW)
        int slt = s & 3;
        u64 pv; short* ps = (short*)&pv;
#pragma unroll
        for (int r=0; r<4; ++r) ps[r] = f2bf(h0v[ctx][r]);
        __hip_atomic_store((u64*)(ring0 + ((slt*32+g)*256 + colg)*16 + quad*4), pv,
                           __ATOMIC_RELAXED, __HIP_MEMORY_SCOPE_AGENT);
      }
      if (doL1){
        float pr[4];
#pragma unroll
        for (int r=0; r<4; ++r){
          float iv = sigm (acc1[0][r] + bia1[0]);
          float fv = sigm (acc1[1][r] + bia1[1]);
          float gv = tanhx(acc1[2][r] + bia1[2]);
          float ov = sigm (acc1[3][r] + bia1[3]);
          float cc = fv*c1s[ctx][r] + iv*gv;
          c1s[ctx][r] = cc;
          float h = ov * tanhx(cc);
          h1v[ctx][r] = h;
          pr[r] = h * wo;
        }
        int slt = (s-1) & 3;
        u64 pv; short* ps = (short*)&pv;
#pragma unroll
        for (int r=0; r<4; ++r) ps[r] = f2bf(h1v[ctx][r]);
        __hip_atomic_store((u64*)(ring1 + ((slt*32+g)*256 + colg)*16 + quad*4), pv,
                           __ATOMIC_RELAXED, __HIP_MEMORY_SCOPE_AGENT);
#pragma unroll
        for (int m=1; m<16; m<<=1){
#pragma unroll
          for (int r=0; r<4; ++r) pr[r] += __shfl_xor(pr[r], m, 64);
        }
        if (col16 == 0){
#pragma unroll
          for (int r=0; r<4; ++r) outacc[ctx][quad*4 + r][w] = pr[r];
        }
      }
    }

    __syncthreads();   // B1: compiler drains vmcnt(0) before s_barrier => all
                       // waves' ring stores are complete; LDS reads done.

    // flags: one RELEASE store per context (single lane each)
    if (s < TT && tid < 2)
      __hip_atomic_store(&flags[(gctx[tid]*4+c)*32], (unsigned)(s+1),
                         __ATOMIC_RELEASE, __HIP_MEMORY_SCOPE_AGENT);

    // own h into LDS frags; stage x_{s+1}; out partial for t=s-1
#pragma unroll
    for (int ctx=0; ctx<2; ++ctx){
      if (doL0){
#pragma unroll
        for (int r=0; r<4; ++r) AH0[ctx][fragAddr(colg, quad*4 + r)] = f2bf(h0v[ctx][r]);
      }
      if (doL1 && s < TT){
#pragma unroll
        for (int r=0; r<4; ++r) AH1[ctx][fragAddr(colg, quad*4 + r)] = f2bf(h1v[ctx][r]);
      }
      if (s+1 < TT){
        int m = tid >> 4, d = tid & 15;
        AX[ctx][fragAddr(d, m)] = f2bf(xf[ctx]);
      }
      if (doL1 && tid < 16)
        outLDS[ctx][s-1][tid] = outacc[ctx][tid][0] + outacc[ctx][tid][1]
                              + outacc[ctx][tid][2] + outacc[ctx][tid][3];
    }

    // ---- wait partners: 3 lanes per context, concurrent; acquire exit ----
    if (s < TT){
      if (tid < 3 || (tid >= 4 && tid < 7)){
        int ctx = (tid >= 4) ? 1 : 0;
        int pi  = (tid >= 4) ? (tid - 4) : tid;
        int p = (c + 1 + pi) & 3;
        const unsigned* fp = flags + (gctx[ctx]*4+p)*32;
        unsigned target = (unsigned)(s+1);
        unsigned spin = 0;
        while (true){
          if (__hip_atomic_load(fp, __ATOMIC_RELAXED, __HIP_MEMORY_SCOPE_AGENT) >= target){
            (void)__hip_atomic_load(fp, __ATOMIC_ACQUIRE, __HIP_MEMORY_SCOPE_AGENT);
            break;
          }
          if (((++spin) & 63u) == 0u){
            if (__hip_atomic_load(fp, __ATOMIC_ACQUIRE, __HIP_MEMORY_SCOPE_AGENT) >= target)
              break;
          }
        }
      }
      __syncthreads();  // B2: flags observed + caches invalidated

      int qd = tid & 3;
      int cl = (tid >> 2) & 63;
      int slt0 = s & 3;
      int slt1 = (s-1) & 3;
#pragma unroll
      for (int ctx=0; ctx<2; ++ctx){
        int g = gctx[ctx];
#pragma unroll
        for (int pi=0; pi<3; ++pi){
          int p = (c + 1 + pi) & 3;
          int k = p*64 + cl;
          u64 v0 = *(const u64*)(ring0 + ((slt0*32+g)*256 + k)*16 + qd*4);
          short* sv = (short*)&v0;
#pragma unroll
          for (int r=0; r<4; ++r) AH0[ctx][fragAddr(k, qd*4 + r)] = sv[r];
          if (s >= 1){
            u64 v1 = *(const u64*)(ring1 + ((slt1*32+g)*256 + k)*16 + qd*4);
            short* sw = (short*)&v1;
#pragma unroll
            for (int r=0; r<4; ++r) AH1[ctx][fragAddr(k, qd*4 + r)] = sw[r];
          }
        }
      }
    }
    __syncthreads();  // B3: LDS ready for next superstep
  }

  // ---- final out accumulation (RMWs only here, off the critical loop) ----
  const float bos = bo[0];
#pragma unroll
  for (int ctx=0; ctx<2; ++ctx){
    int rowbase = gctx[ctx]*16;
    for (int i = tid; i < TT*16; i += 256){
      int t = i >> 4, row = i & 15;
      float v = outLDS[ctx][t][row];
      if (c == 0) v += bos;
      atomicAdd(&out[(rowbase + row)*TT + t], v);
    }
  }
}

// ---------------- launch ----------------
extern "C" void kernel_launch(void* const* d_in, const int* in_sizes, int n_in,
                              void* d_out, int out_size, void* d_ws, size_t ws_size,
                              hipStream_t stream)
{
  const float* x    = (const float*)d_in[0];
  const float* xs   = (const float*)d_in[1];
  const float* Wih0 = (const float*)d_in[2];
  const float* Whh0 = (const float*)d_in[3];
  const float* bih0 = (const float*)d_in[4];
  const float* bhh0 = (const float*)d_in[5];
  const float* Wih1 = (const float*)d_in[6];
  const float* Whh1 = (const float*)d_in[7];
  const float* bih1 = (const float*)d_in[8];
  const float* bhh1 = (const float*)d_in[9];
  const float* Ws   = (const float*)d_in[10];
  const float* bs   = (const float*)d_in[11];
  const float* Wo   = (const float*)d_in[12];
  const float* bo   = (const float*)d_in[13];
  float* out = (float*)d_out;

  char* ws = (char*)d_ws;
  short*    Wb0   = (short*)(ws);                // 589824
  short*    Wb1   = (short*)(ws + 589824);       // 1048576 -> 1638400
  float*    h0i   = (float*)(ws + 1638400);      // 524288  -> 2162688
  float*    b0cp  = (float*)(ws + 2162688);      // 4096    -> 2166784
  float*    b1cp  = (float*)(ws + 2166784);      // 4096    -> 2170880
  short*    ring0 = (short*)(ws + 2170880);      // 1048576 -> 3219456
  short*    ring1 = (short*)(ws + 3219456);      // 1048576 -> 4268032
  unsigned* flags = (unsigned*)(ws + 4268032);   // 16384   -> ~4.28 MB total

  int nswz = 16*36*512 + 16*64*512;
  hipLaunchKernelGGL(prep_weights, dim3((nswz+255)/256), dim3(256), 0, stream,
                     Wih0, Whh0, Wih1, Whh1, Wb0, Wb1);
  hipLaunchKernelGGL(prep_h0, dim3(512), dim3(256), 0, stream, xs, Ws, bs, h0i);
  hipLaunchKernelGGL(prep_bias, dim3(8), dim3(256), 0, stream, bih0, bhh0, bih1, bhh1, b0cp, b1cp);
  hipLaunchKernelGGL(prep_zero, dim3((BB*TT+255)/256), dim3(256), 0, stream, out, flags);

  hipLaunchKernelGGL(lstm_fused, dim3(64), dim3(256), 0, stream,
                     Wb0, Wb1, h0i, b0cp, b1cp, x, Wo, bo,
                     ring0, ring1, flags, out);
}

// Round 8
// 3428.014 us; speedup vs baseline: 1.5154x; 1.5154x over previous
//
#include <hip/hip_runtime.h>

#define TT 365
#define BB 512
#define DD 16
#define HH 256
#define SS 32

typedef __attribute__((ext_vector_type(8))) short short8;
typedef __attribute__((ext_vector_type(4))) float f32x4;
typedef unsigned long long u64;

__device__ __host__ inline short f2bf(float f){
  union { float f; unsigned u; } v; v.f = f;
  unsigned r = v.u + 0x7FFFu + ((v.u >> 16) & 1u);
  return (short)(r >> 16);
}
__device__ inline float sigm(float x){ return 1.0f/(1.0f+__expf(-x)); }
__device__ inline float tanhx(float x){ return 2.0f/(1.0f+__expf(-2.0f*x)) - 1.0f; }

// A-fragment address (shorts) in an 8KB K=256 region for mfma_16x16x32 A-layout.
__device__ inline int fragAddr(int k, int m){
  return ((k>>5)*512) + ((((k&31)>>3)*16 + m)*8) + (k&7);
}

// pack 2 bf16 + 32-bit step tag into one u64 (value-tagged exchange word)
__device__ inline u64 pack2(float a, float b, unsigned tag){
  unsigned lo = (unsigned)(unsigned short)f2bf(a)
              | ((unsigned)(unsigned short)f2bf(b) << 16);
  return (u64)lo | ((u64)tag << 32);
}

// ---------------- prep kernels ----------------
__global__ void prep_weights(const float* __restrict__ Wih0, const float* __restrict__ Whh0,
                             const float* __restrict__ Wih1, const float* __restrict__ Whh1,
                             short* __restrict__ Wb0, short* __restrict__ Wb1)
{
  int idx = blockIdx.x*blockDim.x + threadIdx.x;
  const int n0 = 16*36*512;
  const int n1 = 16*64*512;
  if (idx < n0){
    int frag = idx >> 9, pos = idx & 511;
    int lane = pos >> 3, jj = pos & 7;
    int slot = frag / 36, rem = frag % 36;
    int ks = rem >> 2, nt = rem & 3;
    int n = nt*256 + slot*16 + (lane & 15);
    float v = 0.0f;
    if (ks == 0){
      int k32 = (lane>>4)*8 + jj;
      if (k32 < 16) v = Wih0[n*16 + k32];
    } else {
      int k = (ks-1)*32 + (lane>>4)*8 + jj;
      v = Whh0[n*256 + k];
    }
    Wb0[idx] = f2bf(v);
  } else if (idx < n0 + n1){
    int e = idx - n0;
    int frag = e >> 9, pos = e & 511;
    int lane = pos >> 3, jj = pos & 7;
    int slot = frag >> 6, rem = frag & 63;
    int ks = rem >> 2, nt = rem & 3;
    int n = nt*256 + slot*16 + (lane & 15);
    int k = ks*32 + (lane>>4)*8 + jj;
    float v = (k < 256) ? Wih1[n*256 + k] : Whh1[n*256 + (k-256)];
    Wb1[e] = f2bf(v);
  }
}

__global__ void prep_h0(const float* __restrict__ xs, const float* __restrict__ Ws,
                        const float* __restrict__ bs, float* __restrict__ h0init)
{
  int i = blockIdx.x*blockDim.x + threadIdx.x;
  int b = i >> 8, jj = i & 255;
  float s = bs[jj];
  const float* xr = xs + b*SS;
  const float* wr = Ws + jj*SS;
#pragma unroll
  for (int q=0;q<SS;++q) s += xr[q]*wr[q];
  h0init[i] = s;
}

__global__ void prep_bias(const float* __restrict__ a0, const float* __restrict__ a1,
                          const float* __restrict__ a2, const float* __restrict__ a3,
                          float* __restrict__ b0o, float* __restrict__ b1o)
{
  int i = threadIdx.x + blockIdx.x*blockDim.x;
  if (i < 1024) b0o[i] = a0[i] + a1[i];
  else if (i < 2048) b1o[i-1024] = a2[i-1024] + a3[i-1024];
}

__global__ void prep_zero(float* __restrict__ out)
{
  int i = blockIdx.x*blockDim.x + threadIdx.x;
  if (i < BB*TT) out[i] = 0.0f;
}

// ---------------- persistent fused LSTM ----------------
// 128 blocks x 256 threads; g = bid&31 (16 batch rows), c = bid>>5 (64 hidden cols).
// Weights register/AGPR-resident. Lag pipeline: superstep s = L0@t=s + L1@t=s-1.
// Exchange: value-tagged ring words (2 bf16 + step tag per u64).
//   publish = relaxed agent-scope atomic store (fire-and-forget; r6-proven)
//   poll    = relaxed agent-scope atomic load on the data words (r4-proven to
//             observe remote agent stores), escalating to an ACQUIRE load every
//             32 misses (deadlock-proof safety valve; r4-proven fresh).
// No flags, no fences, no RMWs, no vmcnt drains in the loop; 2 barriers/step.
// 4 ring slots: slot s&3 overwritten at s+4 only after causal completion of all
// partners' slot-s reads (publish(s+3) implies read(slot s) done). 0xAA poison
// tag = 0xAAAAAAAA > 365 -> never matches.
__global__ __launch_bounds__(256, 1) void lstm_fused(
    const short* __restrict__ Wb0, const short* __restrict__ Wb1,
    const float* __restrict__ h0i, const float* __restrict__ b0c,
    const float* __restrict__ b1c, const float* __restrict__ x,
    const float* __restrict__ Wo, const float* __restrict__ bo,
    u64* __restrict__ ring0, u64* __restrict__ ring1,
    float* __restrict__ out)
{
  __shared__ alignas(16) short AX[512];     // x_t frags, K=32 (k>=16 zero)
  __shared__ alignas(16) short AH0[4096];   // h0[t-1] frags, K=256
  __shared__ alignas(16) short AH1[4096];   // h1[t-2] frags, K=256
  __shared__ float outacc[16][4];
  __shared__ float outLDS[TT][16];

  const int tid  = threadIdx.x;
  const int w    = tid >> 6;
  const int lane = tid & 63;
  const int col16= lane & 15;
  const int quad = lane >> 4;
  const int c    = blockIdx.x >> 5;
  const int g    = blockIdx.x & 31;
  const int rowbase = g * 16;
  const int slot = c*4 + w;
  const int colg = slot*16 + col16;

  // ---- register-resident weight fragments ----
  short8 F0[36], F1[64];
  {
    const short8* p0 = (const short8*)Wb0 + slot*36*64 + lane;
#pragma unroll
    for (int f=0; f<36; ++f) F0[f] = p0[f*64];
    const short8* p1 = (const short8*)Wb1 + slot*64*64 + lane;
#pragma unroll
    for (int f=0; f<64; ++f) F1[f] = p1[f*64];
  }
  float bia0[4], bia1[4];
#pragma unroll
  for (int nt=0; nt<4; ++nt){
    bia0[nt] = b0c[nt*256 + slot*16 + col16];
    bia1[nt] = b1c[nt*256 + slot*16 + col16];
  }
  const float wo = Wo[colg];

  // ---- init states + LDS ----
  float c0[4], c1[4];
#pragma unroll
  for (int r=0; r<4; ++r){
    c0[r] = h0i[(rowbase + quad*4 + r)*HH + colg];
    c1[r] = c0[r];
  }
  for (int i = tid; i < 4096; i += 256){
    int m = i >> 8, k = i & 255;
    short v = f2bf(h0i[(rowbase+m)*HH + k]);
    AH0[fragAddr(k,m)] = v;
    AH1[fragAddr(k,m)] = v;
  }
  {
    int m = tid >> 4, d = tid & 15;
    AX[fragAddr(d, m)]      = f2bf(x[(rowbase+m)*TT*DD + d]);
    AX[fragAddr(16 + d, m)] = 0;
  }
  __syncthreads();

  const f32x4 zero = {0.0f,0.0f,0.0f,0.0f};

  for (int s=0; s<=TT; ++s){
    const bool doL0 = (s < TT);
    const bool doL1 = (s >= 1);

    // prefetch x_{s+1} (hidden under MFMAs; caches stay warm)
    float xf = 0.0f;
    if (s+1 < TT){
      int m = tid >> 4, d = tid & 15;
      xf = x[(rowbase+m)*TT*DD + (s+1)*DD + d];
    }

    // ---- MFMA phase ----
    f32x4 acc0[4], acc1[4];
#pragma unroll
    for (int nt=0; nt<4; ++nt){ acc0[nt]=zero; acc1[nt]=zero; }
    if (doL0){
      short8 a = *(const short8*)(AX + lane*8);
#pragma unroll
      for (int nt=0; nt<4; ++nt)
        acc0[nt] = __builtin_amdgcn_mfma_f32_16x16x32_bf16(a, F0[nt], acc0[nt], 0,0,0);
    }
#pragma unroll
    for (int ks=0; ks<8; ++ks){
      short8 a = *(const short8*)(AH0 + ks*512 + lane*8);
      if (doL0){
#pragma unroll
        for (int nt=0; nt<4; ++nt)
          acc0[nt] = __builtin_amdgcn_mfma_f32_16x16x32_bf16(a, F0[(ks+1)*4+nt], acc0[nt], 0,0,0);
      }
      if (doL1){
#pragma unroll
        for (int nt=0; nt<4; ++nt)
          acc1[nt] = __builtin_amdgcn_mfma_f32_16x16x32_bf16(a, F1[ks*4+nt], acc1[nt], 0,0,0);
      }
    }
    if (doL1){
#pragma unroll
      for (int ks=0; ks<8; ++ks){
        short8 a = *(const short8*)(AH1 + ks*512 + lane*8);
#pragma unroll
        for (int nt=0; nt<4; ++nt)
          acc1[nt] = __builtin_amdgcn_mfma_f32_16x16x32_bf16(a, F1[32+ks*4+nt], acc1[nt], 0,0,0);
      }
    }

    // ---- L0 epilogue + immediate tagged publish (relaxed stores, no RMW) ----
    float h0v[4], h1v[4];
    if (doL0){
#pragma unroll
      for (int r=0; r<4; ++r){
        float iv = sigm (acc0[0][r] + bia0[0]);
        float fv = sigm (acc0[1][r] + bia0[1]);
        float gv = tanhx(acc0[2][r] + bia0[2]);
        float ov = sigm (acc0[3][r] + bia0[3]);
        float cc = fv*c0[r] + iv*gv;
        c0[r] = cc;
        h0v[r] = ov * tanhx(cc);
      }
      u64 base = (u64)(((s&3)*32+g)*256 + colg)*8 + quad*2;
      __hip_atomic_store(ring0 + base + 0, pack2(h0v[0], h0v[1], (unsigned)(s+1)),
                         __ATOMIC_RELAXED, __HIP_MEMORY_SCOPE_AGENT);
      __hip_atomic_store(ring0 + base + 1, pack2(h0v[2], h0v[3], (unsigned)(s+1)),
                         __ATOMIC_RELAXED, __HIP_MEMORY_SCOPE_AGENT);
    }
    // ---- L1 epilogue + tagged publish + out partial ----
    if (doL1){
      float pr[4];
#pragma unroll
      for (int r=0; r<4; ++r){
        float iv = sigm (acc1[0][r] + bia1[0]);
        float fv = sigm (acc1[1][r] + bia1[1]);
        float gv = tanhx(acc1[2][r] + bia1[2]);
        float ov = sigm (acc1[3][r] + bia1[3]);
        float cc = fv*c1[r] + iv*gv;
        c1[r] = cc;
        float h = ov * tanhx(cc);
        h1v[r] = h;
        pr[r] = h * wo;
      }
      u64 base = (u64)((((s-1)&3)*32+g)*256 + colg)*8 + quad*2;
      __hip_atomic_store(ring1 + base + 0, pack2(h1v[0], h1v[1], (unsigned)s),
                         __ATOMIC_RELAXED, __HIP_MEMORY_SCOPE_AGENT);
      __hip_atomic_store(ring1 + base + 1, pack2(h1v[2], h1v[3], (unsigned)s),
                         __ATOMIC_RELAXED, __HIP_MEMORY_SCOPE_AGENT);
#pragma unroll
      for (int m=1; m<16; m<<=1){
#pragma unroll
        for (int r=0; r<4; ++r) pr[r] += __shfl_xor(pr[r], m, 64);
      }
      if (col16 == 0){
#pragma unroll
        for (int r=0; r<4; ++r) outacc[quad*4 + r][w] = pr[r];
      }
    }

    __syncthreads();   // A: all LDS reads of this step done

    // own h into LDS frags; stage x_{s+1}; out partial for t=s-1
    if (doL0){
#pragma unroll
      for (int r=0; r<4; ++r) AH0[fragAddr(colg, quad*4 + r)] = f2bf(h0v[r]);
    }
    if (doL1 && s < TT){
#pragma unroll
      for (int r=0; r<4; ++r) AH1[fragAddr(colg, quad*4 + r)] = f2bf(h1v[r]);
    }
    if (s+1 < TT){
      int m = tid >> 4, d = tid & 15;
      AX[fragAddr(d, m)] = f2bf(xf);
    }
    if (doL1 && tid < 16)
      outLDS[s-1][tid] = outacc[tid][0] + outacc[tid][1] + outacc[tid][2] + outacc[tid][3];

    // ---- poll partner tagged words (relaxed loads; acquire escalation) ----
    if (s < TT){
      const u64* r0b = ring0 + (u64)((s&3)*32+g)*2048;
      const u64* r1b = ring1 + (u64)(((s-1)&3)*32+g)*2048;
      const unsigned tag0 = (unsigned)(s+1);
      const unsigned tag1 = (unsigned)s;
      unsigned need0 = 0x3F, need1 = (s >= 1) ? 0x3F : 0;
      u64 w0v[6], w1v[6];
      int offs[6];
#pragma unroll
      for (int j=0; j<6; ++j){
        int i2 = tid + 256*j;                     // 0..1535
        int p   = (c + 1 + (i2>>9)) & 3;          // partner
        offs[j] = (p*64 + ((i2>>3)&63))*8 + ((i2>>1)&3)*2 + (i2&1);
      }
      unsigned spin = 0;
      while (need0 | need1){
        bool esc = (((++spin) & 31u) == 0u);
#pragma unroll
        for (int j=0; j<6; ++j){
          if (need0 & (1u<<j)){
            u64 v = esc
              ? __hip_atomic_load(r0b + offs[j], __ATOMIC_ACQUIRE, __HIP_MEMORY_SCOPE_AGENT)
              : __hip_atomic_load(r0b + offs[j], __ATOMIC_RELAXED, __HIP_MEMORY_SCOPE_AGENT);
            if ((unsigned)(v>>32) == tag0){ w0v[j] = v; need0 &= ~(1u<<j); }
          }
          if (need1 & (1u<<j)){
            u64 v = esc
              ? __hip_atomic_load(r1b + offs[j], __ATOMIC_ACQUIRE, __HIP_MEMORY_SCOPE_AGENT)
              : __hip_atomic_load(r1b + offs[j], __ATOMIC_RELAXED, __HIP_MEMORY_SCOPE_AGENT);
            if ((unsigned)(v>>32) == tag1){ w1v[j] = v; need1 &= ~(1u<<j); }
          }
        }
      }
#pragma unroll
      for (int j=0; j<6; ++j){
        int i2 = tid + 256*j;
        int p = (c + 1 + (i2>>9)) & 3;
        int k = p*64 + ((i2>>3)&63);
        int m = ((i2>>1)&3)*4 + (i2&1)*2;
        AH0[fragAddr(k, m)]   = (short)(w0v[j] & 0xFFFF);
        AH0[fragAddr(k, m+1)] = (short)((w0v[j] >> 16) & 0xFFFF);
        if (s >= 1){
          AH1[fragAddr(k, m)]   = (short)(w1v[j] & 0xFFFF);
          AH1[fragAddr(k, m+1)] = (short)((w1v[j] >> 16) & 0xFFFF);
        }
      }
    }
    __syncthreads();   // B: LDS ready for next superstep
  }

  // ---- final out accumulation (RMWs only here, off the critical loop) ----
  const float bos = bo[0];
  for (int i = tid; i < TT*16; i += 256){
    int t = i >> 4, row = i & 15;
    float v = outLDS[t][row];
    if (c == 0) v += bos;
    atomicAdd(&out[(rowbase + row)*TT + t], v);
  }
}

// ---------------- launch ----------------
extern "C" void kernel_launch(void* const* d_in, const int* in_sizes, int n_in,
                              void* d_out, int out_size, void* d_ws, size_t ws_size,
                              hipStream_t stream)
{
  const float* x    = (const float*)d_in[0];
  const float* xs   = (const float*)d_in[1];
  const float* Wih0 = (const float*)d_in[2];
  const float* Whh0 = (const float*)d_in[3];
  const float* bih0 = (const float*)d_in[4];
  const float* bhh0 = (const float*)d_in[5];
  const float* Wih1 = (const float*)d_in[6];
  const float* Whh1 = (const float*)d_in[7];
  const float* bih1 = (const float*)d_in[8];
  const float* bhh1 = (const float*)d_in[9];
  const float* Ws   = (const float*)d_in[10];
  const float* bs   = (const float*)d_in[11];
  const float* Wo   = (const float*)d_in[12];
  const float* bo   = (const float*)d_in[13];
  float* out = (float*)d_out;

  char* ws = (char*)d_ws;
  short*    Wb0   = (short*)(ws);                // 589824
  short*    Wb1   = (short*)(ws + 589824);       // 1048576 -> 1638400
  float*    h0i   = (float*)(ws + 1638400);      // 524288  -> 2162688
  float*    b0cp  = (float*)(ws + 2162688);      // 4096    -> 2166784
  float*    b1cp  = (float*)(ws + 2166784);      // 4096    -> 2170880
  u64*      ring0 = (u64*)(ws + 2170880);        // 2097152 -> 4268032
  u64*      ring1 = (u64*)(ws + 4268032);        // 2097152 -> 6365184 (~6.37 MB)

  int nswz = 16*36*512 + 16*64*512;
  hipLaunchKernelGGL(prep_weights, dim3((nswz+255)/256), dim3(256), 0, stream,
                     Wih0, Whh0, Wih1, Whh1, Wb0, Wb1);
  hipLaunchKernelGGL(prep_h0, dim3(512), dim3(256), 0, stream, xs, Ws, bs, h0i);
  hipLaunchKernelGGL(prep_bias, dim3(8), dim3(256), 0, stream, bih0, bhh0, bih1, bhh1, b0cp, b1cp);
  hipLaunchKernelGGL(prep_zero, dim3((BB*TT+255)/256), dim3(256), 0, stream, out);

  hipLaunchKernelGGL(lstm_fused, dim3(128), dim3(256), 0, stream,
                     Wb0, Wb1, h0i, b0cp, b1cp, x, Wo, bo,
                     ring0, ring1, out);
}